// Round 16
// baseline (199.154 us; speedup 1.0000x reference)
//
#include <hip/hip_runtime.h>
#include <stdint.h>

// ---------------------------------------------------------------------------
// TimeCondAttention on MI355X (gfx950)
// B=2, N=2048, DIM=512, H=8, DH=64, TIME_DIM=512
// R16: BARRIER-FREE k_attn (independence lever, cleanly isolated):
//   - K/V fragments read global->VGPR (L2-resident per XCD), consumed
//     immediately by MFMA (transient regs; no launch_bounds clamp = no R6 trap)
//   - LDS = per-wave bias ring (2x4KB) + per-wave P (2KB) = 40KB/block
//     -> 4 blocks/CU, 16 independent waves/CU, ZERO s_barrier
//   - one manual wait/iter: phase-C vmcnt(16) (bias(kt+1)4 + km4 + K8 newer)
//   - k_gemm_out: duplicate Ah stage removed
//   - numerics identical to R15 (absmax 1.22e-4)
// ---------------------------------------------------------------------------

using s16x8 = __attribute__((ext_vector_type(8))) short;
using f32x4 = __attribute__((ext_vector_type(4))) float;
using u16x4 = __attribute__((ext_vector_type(4))) unsigned short;
using u32x2 = __attribute__((ext_vector_type(2))) unsigned int;

#define EPSV 1e-5f
#define NEGV 1e6f
#define L2E  1.44269504088896341f
// q-projection scale: 0.125 * log2(e)
#define QSCL 0.18033688011112043f

__device__ __forceinline__ unsigned short f2bf(float f) {
    unsigned int u = __float_as_uint(f);
    u += 0x7FFFu + ((u >> 16) & 1u);   // RNE (inputs finite)
    return (unsigned short)(u >> 16);
}
__device__ __forceinline__ float bf2f(unsigned short s) {
    return __uint_as_float((unsigned int)s << 16);
}

__device__ __forceinline__ void gl_lds16(const void* g, void* l) {
    __builtin_amdgcn_global_load_lds((const __attribute__((address_space(1))) void*)g,
                                     (__attribute__((address_space(3))) void*)l, 16, 0, 0);
}

__device__ __forceinline__ f32x4 mfma_bf16(s16x8 a, s16x8 b, f32x4 c) {
    return __builtin_amdgcn_mfma_f32_16x16x32_bf16(a, b, c, 0, 0, 0);
}

// ---------------- K0: fused weight-prep + time GEMV -------------------------
__global__ void k_pt(const float* __restrict__ w_q, const float* __restrict__ w_kv,
                     const float* __restrict__ w_out,
                     const float* __restrict__ timev, const float* __restrict__ w_time,
                     const float* __restrict__ b_time,
                     unsigned short* __restrict__ wq, unsigned short* __restrict__ wkv,
                     unsigned short* __restrict__ wo_h, unsigned short* __restrict__ wo_l,
                     float* __restrict__ tc) {
    if (blockIdx.x < 4096) {
        int idx = blockIdx.x * 256 + threadIdx.x;     // total 1,048,576 exactly
        if (idx < 262144) {
            wq[idx] = f2bf(w_q[idx]);
        } else if (idx < 786432) {
            int i = idx - 262144;
            wkv[i] = f2bf(w_kv[i]);
        } else {
            int i = idx - 786432;
            float v = w_out[i];
            unsigned short h = f2bf(v);
            wo_h[i] = h;
            wo_l[i] = f2bf(v - bf2f(h));
        }
    } else {
        int bid = blockIdx.x - 4096;                  // 0..511
        int wid = threadIdx.x >> 6, lane = threadIdx.x & 63;
        int b = bid >> 8;
        int j = (bid & 255) * 4 + wid;                // 0..1023
        const float* tv = timev + b * 512;
        const float* wr = w_time + (size_t)j * 512;
        float acc = 0.f;
#pragma unroll
        for (int i = 0; i < 8; ++i) {
            int k = i * 64 + lane;
            float t = tv[k];
            float s = t / (1.f + __expf(-t));         // silu
            acc += s * wr[k];
        }
#pragma unroll
        for (int m = 32; m >= 1; m >>= 1) acc += __shfl_xor(acc, m);
        if (lane == 0) tc[b * 1024 + j] = acc + b_time[j];
    }
}

// ---------------- K2: LayerNorm + FiLM + seq_mask, wave-per-row -------------
__global__ void k_lnfilm(const float* __restrict__ x, const float* __restrict__ gamma,
                         const float* __restrict__ seq_mask, const float* __restrict__ tc,
                         unsigned short* __restrict__ xbf, unsigned short* __restrict__ xnbf) {
    int row = blockIdx.x * 4 + (threadIdx.x >> 6);     // grid 1024, 4 rows/block
    int lane = threadIdx.x & 63;
    int b = row >> 11;
    const float* xr = x + (size_t)row * 512 + lane * 8;
    f32x4 x0 = *(const f32x4*)(xr);
    f32x4 x1 = *(const f32x4*)(xr + 4);
    float s = (x0[0] + x0[1]) + (x0[2] + x0[3]) + (x1[0] + x1[1]) + (x1[2] + x1[3]);
    float sq = x0[0] * x0[0];
    sq = __builtin_fmaf(x0[1], x0[1], sq);
    sq = __builtin_fmaf(x0[2], x0[2], sq);
    sq = __builtin_fmaf(x0[3], x0[3], sq);
    sq = __builtin_fmaf(x1[0], x1[0], sq);
    sq = __builtin_fmaf(x1[1], x1[1], sq);
    sq = __builtin_fmaf(x1[2], x1[2], sq);
    sq = __builtin_fmaf(x1[3], x1[3], sq);
#pragma unroll
    for (int m = 32; m >= 1; m >>= 1) { s += __shfl_xor(s, m); sq += __shfl_xor(sq, m); }
    float mu = s * (1.f / 512.f);
    float var = sq * (1.f / 512.f) - mu * mu;
    float rs = rsqrtf(var + EPSV);
    float qm = seq_mask[row];
    int j = lane * 8;
    const float* scb = tc + b * 1024 + j;
    f32x4 g0 = *(const f32x4*)(gamma + j);
    f32x4 g1 = *(const f32x4*)(gamma + j + 4);
    f32x4 c0 = *(const f32x4*)(scb);
    f32x4 c1 = *(const f32x4*)(scb + 4);
    f32x4 h0 = *(const f32x4*)(scb + 512);
    f32x4 h1 = *(const f32x4*)(scb + 516);
    u16x4 n0, n1, v0, v1;
#pragma unroll
    for (int e = 0; e < 4; ++e) {
        float o0 = ((x0[e] - mu) * rs * g0[e]) * (c0[e] + 1.f) + h0[e];
        float o1 = ((x1[e] - mu) * rs * g1[e]) * (c1[e] + 1.f) + h1[e];
        n0[e] = f2bf(o0 * qm);
        n1[e] = f2bf(o1 * qm);
        v0[e] = f2bf(x0[e]);
        v1[e] = f2bf(x1[e]);
    }
    size_t base = (size_t)row * 512 + j;
    *(u16x4*)(xnbf + base)     = n0;
    *(u16x4*)(xnbf + base + 4) = n1;
    *(u16x4*)(xbf + base)      = v0;
    *(u16x4*)(xbf + base + 4)  = v1;
}

// ---------------- K3: fused q-proj + kv-proj GEMMs ---------------------------
__launch_bounds__(256)
__global__ void k_gemm2(const unsigned short* __restrict__ xnbf,
                        const unsigned short* __restrict__ xbf,
                        const unsigned short* __restrict__ wq,
                        const unsigned short* __restrict__ wkv,
                        unsigned short* __restrict__ qb,
                        unsigned short* __restrict__ kb,
                        unsigned short* __restrict__ vtb) {
    __shared__ unsigned short a_t[128 * 64];
    __shared__ unsigned short b_t[128 * 64];
    int tid = threadIdx.x, lane = tid & 63, wid = tid >> 6;
    int lc = lane & 15, lq = lane >> 4;
    int wr = wid >> 1, wc = wid & 1;
    bool isQ = blockIdx.y < 4;
    int m0 = blockIdx.x * 128;
    int n0 = (isQ ? blockIdx.y : blockIdx.y - 4) * 128;
    const unsigned short* A = isQ ? xnbf : xbf;
    const unsigned short* W = isQ ? wq : wkv;
    f32x4 acc[4][4];
#pragma unroll
    for (int i = 0; i < 4; ++i)
#pragma unroll
        for (int jn = 0; jn < 4; ++jn)
#pragma unroll
            for (int e = 0; e < 4; ++e) acc[i][jn][e] = 0.f;
    const unsigned short* Ab = A + (size_t)m0 * 512;
    const unsigned short* Wb = W + (size_t)n0 * 512;
    int wbase = wid * 64;
    for (int kt = 0; kt < 8; ++kt) {
        __syncthreads();
#pragma unroll
        for (int i = 0; i < 4; ++i) {
            int p = i * 256 + wbase + lane;
            int row = p >> 3, ls = (p & 7) ^ (row & 7);
            gl_lds16(Ab + (size_t)row * 512 + kt * 64 + ls * 8, a_t + (i * 256 + wbase) * 8);
            gl_lds16(Wb + (size_t)row * 512 + kt * 64 + ls * 8, b_t + (i * 256 + wbase) * 8);
        }
        __syncthreads();
        s16x8 af[4][2], bw[4][2];
        const char* ab = (const char*)a_t;
        const char* bb = (const char*)b_t;
#pragma unroll
        for (int mf = 0; mf < 4; ++mf) {
            int row = wr * 64 + mf * 16 + lc;
            int key = (row & 7) << 4;
            af[mf][0] = *(const s16x8*)(ab + row * 128 + ((lq * 16) ^ key));
            af[mf][1] = *(const s16x8*)(ab + row * 128 + ((64 + lq * 16) ^ key));
        }
#pragma unroll
        for (int nf = 0; nf < 4; ++nf) {
            int row = wc * 64 + nf * 16 + lc;
            int key = (row & 7) << 4;
            bw[nf][0] = *(const s16x8*)(bb + row * 128 + ((lq * 16) ^ key));
            bw[nf][1] = *(const s16x8*)(bb + row * 128 + ((64 + lq * 16) ^ key));
        }
#pragma unroll
        for (int mf = 0; mf < 4; ++mf)
#pragma unroll
            for (int nf = 0; nf < 4; ++nf) {
                acc[mf][nf] = mfma_bf16(af[mf][0], bw[nf][0], acc[mf][nf]);
                acc[mf][nf] = mfma_bf16(af[mf][1], bw[nf][1], acc[mf][nf]);
            }
    }
#pragma unroll
    for (int mf = 0; mf < 4; ++mf)
#pragma unroll
        for (int nf = 0; nf < 4; ++nf) {
            int grow0 = m0 + wr * 64 + mf * 16 + lq * 4;
            int gcol = n0 + wc * 64 + nf * 16 + lc;
            int b = grow0 >> 11, nb = grow0 & 2047;
            if (isQ) {
                int h = gcol >> 6, d = gcol & 63;
#pragma unroll
                for (int r = 0; r < 4; ++r)
                    qb[((size_t)((b * 8 + h) * 2048 + nb + r)) * 64 + d] =
                        f2bf(acc[mf][nf][r] * QSCL);
            } else if (gcol < 512) {
                int h = gcol >> 6, d = gcol & 63;
#pragma unroll
                for (int r = 0; r < 4; ++r)
                    kb[((size_t)((b * 8 + h) * 2048 + nb + r)) * 64 + d] = f2bf(acc[mf][nf][r]);
            } else {
                int jj = gcol & 511;
                int h = jj >> 6, d = jj & 63;
                u16x4 vv;
#pragma unroll
                for (int r = 0; r < 4; ++r) vv[r] = f2bf(acc[mf][nf][r]);
                *(u16x4*)(vtb + ((size_t)((b * 8 + h) * 64 + d)) * 2048 + nb) = vv;
            }
        }
}

// ---------------- K4: barrier-free flash attention ---------------------------
__launch_bounds__(256)
__global__ void k_attn(const unsigned short* __restrict__ qg, const unsigned short* __restrict__ kg,
                       const unsigned short* __restrict__ vt, const float* __restrict__ bias,
                       const float* __restrict__ seq_mask,
                       unsigned short* __restrict__ ah, unsigned short* __restrict__ al) {
    __shared__ __align__(16) char b_ring[2][16384];   // bias ring: 4 waves x 4KB/slot
    __shared__ __align__(16) char scr[4][2048];       // per-wave P scratch

    int tid = threadIdx.x, lane = tid & 63, w = tid >> 6;
    int lc = lane & 15, lq = lane >> 4;

    // XCD mapping: 512 blocks; XCD c hosts bh {2c,2c+1} (K/V L2-resident)
    int lin = blockIdx.x;
    int vid = (lin & 7) * 64 + (lin >> 3);
    int bh = vid >> 5;
    int q0 = (vid & 31) * 64 + w * 16;
    int b = bh >> 3, h = bh & 7;

    const unsigned short* qbase = qg + ((size_t)bh * 2048 + q0) * 64;
    s16x8 aq0 = *(const s16x8*)(qbase + lc * 64 + lq * 8);
    s16x8 aq1 = *(const s16x8*)(qbase + lc * 64 + 32 + lq * 8);

    const unsigned short* kb = kg + (size_t)bh * 2048 * 64;
    const unsigned short* vt0 = vt + (size_t)bh * 64 * 2048;
    const float* bqb = bias + ((size_t)bh * 2048 + q0) * 2048;   // wave's 16 rows
    const float* sk = seq_mask + b * 2048;
    const float NEG2 = NEGV * L2E;
    float qm_ = seq_mask[b * 2048 + q0 + lc];

    char* pw = &scr[w][0];
    int swz = (lc & 7) << 4;
    int brow = lane >> 4, bchk = lane & 15;            // bias load mapping

    float mst = -1e30f, lst = 0.f;
    f32x4 acc[4];
#pragma unroll
    for (int df = 0; df < 4; ++df)
#pragma unroll
        for (int e = 0; e < 4; ++e) acc[df][e] = 0.f;

    // bias: instr i = rows 4i..4i+3 of wave's 16; 4x256B contiguous segments.
    auto issue_b = [&](int tile, int slot) {
#pragma unroll
        for (int i = 0; i < 4; ++i) {
            int row = i * 4 + brow;                    // wave-local 0..15
            int kc = bchk ^ (row & 7);                 // 16B chunk index
            gl_lds16(bqb + (size_t)row * 2048 + tile * 64 + kc * 4,
                     (char*)b_ring[slot] + w * 4096 + i * 1024);
        }
    };

    // ---- prologue: bias(0) -> slot0; drain (once; no barrier needed) ----
    issue_b(0, 0);
    __builtin_amdgcn_sched_barrier(0);
    asm volatile("s_waitcnt vmcnt(0)");
    __builtin_amdgcn_sched_barrier(0);

    auto iter = [&](int kt, int par) {
        const int slot_nxt = par ^ 1;

        // ---- phase A: issue bias(kt+1) (oldest vm ops this iter) ----
        {
            int tk = (kt + 1 < 32) ? kt + 1 : 31;
            issue_b(tk, slot_nxt);
        }
        __builtin_amdgcn_sched_barrier(0);

        // ---- phase A2: km from global (L2-resident; compiler-managed wait) ----
        f32x4 km[4];
#pragma unroll
        for (int nf = 0; nf < 4; ++nf)
            km[nf] = *(const f32x4*)(sk + kt * 64 + nf * 16 + lq * 4);
        __builtin_amdgcn_sched_barrier(0);

        // ---- phase B: S^T = K Q^T, K fragments straight from global (L2) ----
        const unsigned short* kkt = kb + (size_t)kt * 64 * 64;
        f32x4 sv[4];
        __builtin_amdgcn_s_setprio(1);
#pragma unroll
        for (int nf = 0; nf < 4; ++nf) {
            s16x8 k0 = *(const s16x8*)(kkt + (nf * 16 + lc) * 64 + lq * 8);
            s16x8 k1 = *(const s16x8*)(kkt + (nf * 16 + lc) * 64 + 32 + lq * 8);
            f32x4 z;
            z[0] = 0.f; z[1] = 0.f; z[2] = 0.f; z[3] = 0.f;
            z = mfma_bf16(k0, aq0, z);
            z = mfma_bf16(k1, aq1, z);
            sv[nf] = z;
        }
        __builtin_amdgcn_s_setprio(0);

        // ---- phase C: bias(kt) from LDS. vmcnt(16): newer ops possibly
        //      outstanding = bias(kt+1)4 + km4 + K8 = 16 -> bias(kt) retired ----
        __builtin_amdgcn_sched_barrier(0);
        asm volatile("s_waitcnt vmcnt(16)");
        __builtin_amdgcn_sched_barrier(0);
        const char* bws = (const char*)b_ring[par] + w * 4096;
        f32x4 bv[4];
#pragma unroll
        for (int nf = 0; nf < 4; ++nf)
            bv[nf] = *(const f32x4*)(bws + lc * 256 + ((((nf << 2) + lq) ^ (lc & 7)) << 4));

        // ---- phase D: bias*log2e + mask penalty (exact 0 when unmasked) ----
#pragma unroll
        for (int nf = 0; nf < 4; ++nf) {
#pragma unroll
            for (int e = 0; e < 4; ++e) {
                float pen = __builtin_fmaf(km[nf][e], qm_, -1.0f) * NEG2;
                sv[nf][e] = __builtin_fmaf(bv[nf][e], L2E, sv[nf][e]) + pen;
            }
        }

        // ---- phase E: online softmax, defer-max, cvt_pk P store ----
        f32x4 m4 = sv[0];
#pragma unroll
        for (int nf = 1; nf < 4; ++nf)
#pragma unroll
            for (int e = 0; e < 4; ++e) m4[e] = fmaxf(m4[e], sv[nf][e]);
        float mx = fmaxf(fmaxf(m4[0], m4[1]), fmaxf(m4[2], m4[3]));
        mx = fmaxf(mx, __shfl_xor(mx, 16));
        mx = fmaxf(mx, __shfl_xor(mx, 32));
        if (!__all(mx <= mst + 11.54f)) {
            float mn = fmaxf(mst, mx);
            float scl = __builtin_amdgcn_exp2f(mst - mn);
            lst *= scl;
#pragma unroll
            for (int df = 0; df < 4; ++df)
#pragma unroll
                for (int e = 0; e < 4; ++e) acc[df][e] *= scl;
            mst = mn;
        }
        float rsum = 0.f;
#pragma unroll
        for (int nf = 0; nf < 4; ++nf) {
            f32x4 p;
#pragma unroll
            for (int e = 0; e < 4; ++e) {
                p[e] = __builtin_amdgcn_exp2f(sv[nf][e] - mst);
                rsum += p[e];
            }
            unsigned int pk01, pk23;
            asm("v_cvt_pk_bf16_f32 %0, %1, %2" : "=v"(pk01) : "v"(p[0]), "v"(p[1]));
            asm("v_cvt_pk_bf16_f32 %0, %1, %2" : "=v"(pk23) : "v"(p[2]), "v"(p[3]));
            u32x2 pkv;
            pkv[0] = pk01; pkv[1] = pk23;
            *(u32x2*)(pw + lc * 128 + ((nf * 32 + lq * 8) ^ swz)) = pkv;
        }
        rsum += __shfl_xor(rsum, 16);
        rsum += __shfl_xor(rsum, 32);
        lst += rsum;

        __builtin_amdgcn_sched_barrier(0);
        asm volatile("s_waitcnt lgkmcnt(0)");   // P visible (wave-local)
        __builtin_amdgcn_sched_barrier(0);      // rule #18

        // ---- phase F: O^T += V^T P^T, V fragments straight from global (L2) ----
        s16x8 ap0 = *(const s16x8*)(pw + lc * 128 + ((lq * 16) ^ swz));
        s16x8 ap1 = *(const s16x8*)(pw + lc * 128 + ((64 + lq * 16) ^ swz));
        const unsigned short* vkt = vt0 + kt * 64;
        __builtin_amdgcn_s_setprio(1);
#pragma unroll
        for (int df = 0; df < 4; ++df) {
            s16x8 v0 = *(const s16x8*)(vkt + (size_t)(df * 16 + lc) * 2048 + lq * 8);
            s16x8 v1 = *(const s16x8*)(vkt + (size_t)(df * 16 + lc) * 2048 + 32 + lq * 8);
            acc[df] = mfma_bf16(v0, ap0, acc[df]);
            acc[df] = mfma_bf16(v1, ap1, acc[df]);
        }
        __builtin_amdgcn_s_setprio(0);
        // (no tail wait, no barrier — waves are fully independent)
    };

    for (int t = 0; t < 16; ++t) {
        iter(2 * t,     0);
        iter(2 * t + 1, 1);
    }
    asm volatile("s_waitcnt vmcnt(0)");   // retire dangling clamped prefetch

    // ---- epilogue: O[q=lc][d], hi/lo bf16 split for precise out-proj ----
    float inv = 1.f / lst;
    size_t rowb = ((size_t)(b * 2048 + q0 + lc)) * 512 + h * 64;
#pragma unroll
    for (int df = 0; df < 4; ++df) {
        u16x4 hi, lo;
#pragma unroll
        for (int r = 0; r < 4; ++r) {
            float o = acc[df][r] * inv;
            unsigned short hb = f2bf(o);
            hi[r] = hb;
            lo[r] = f2bf(o - bf2f(hb));
        }
        *(u16x4*)(ah + rowb + df * 16 + lq * 4) = hi;
        *(u16x4*)(al + rowb + df * 16 + lq * 4) = lo;
    }
}

// ---------------- K5: out proj, 64x128 tile (grid 256 = 1 block/CU) ---------
__launch_bounds__(256)
__global__ void k_gemm_out(const unsigned short* __restrict__ Ah, const unsigned short* __restrict__ Al,
                           const unsigned short* __restrict__ Wh, const unsigned short* __restrict__ Wl,
                           const float* __restrict__ seq_mask, float* __restrict__ out) {
    __shared__ unsigned short ah_t[64 * 32], al_t[64 * 32], bh_t[128 * 32], bl_t[128 * 32];
    int tid = threadIdx.x, lane = tid & 63, wid = tid >> 6;
    int lc = lane & 15, lq = lane >> 4;
    int wc = wid;                                      // 0..3: N-slice of 32
    int m0 = blockIdx.x * 64, n0 = blockIdx.y * 128;
    f32x4 acc[4][2];
#pragma unroll
    for (int i = 0; i < 4; ++i)
#pragma unroll
        for (int jn = 0; jn < 2; ++jn)
#pragma unroll
            for (int e = 0; e < 4; ++e) acc[i][jn][e] = 0.f;
    int wbase = wid * 64;
    for (int kt = 0; kt < 16; ++kt) {
        __syncthreads();
        {
            int p = wbase + lane;
            int row = p >> 2, ls = (p & 3) ^ (row & 3);
            size_t asrc = (size_t)(m0 + row) * 512 + kt * 32 + ls * 8;
            gl_lds16(Ah + asrc, ah_t + wbase * 8);
            gl_lds16(Al + asrc, al_t + wbase * 8);
        }
#pragma unroll
        for (int i = 0; i < 2; ++i) {
            int p = i * 256 + wbase + lane;
            int row = p >> 2, ls = (p & 3) ^ (row & 3);
            size_t bsrc = (size_t)(n0 + row) * 512 + kt * 32 + ls * 8;
            gl_lds16(Wh + bsrc, bh_t + (i * 256 + wbase) * 8);
            gl_lds16(Wl + bsrc, bl_t + (i * 256 + wbase) * 8);
        }
        __syncthreads();
        s16x8 fah[4], fal[4], fbh[2], fbl[2];
#pragma unroll
        for (int mf = 0; mf < 4; ++mf) {
            int row = mf * 16 + lc;
            int off = row * 64 + ((lq * 16) ^ ((row & 3) << 4));
            fah[mf] = *(const s16x8*)((const char*)ah_t + off);
            fal[mf] = *(const s16x8*)((const char*)al_t + off);
        }
#pragma unroll
        for (int nf = 0; nf < 2; ++nf) {
            int row = wc * 32 + nf * 16 + lc;
            int off = row * 64 + ((lq * 16) ^ ((row & 3) << 4));
            fbh[nf] = *(const s16x8*)((const char*)bh_t + off);
            fbl[nf] = *(const s16x8*)((const char*)bl_t + off);
        }
#pragma unroll
        for (int mf = 0; mf < 4; ++mf)
#pragma unroll
            for (int nf = 0; nf < 2; ++nf) {
                acc[mf][nf] = mfma_bf16(fah[mf], fbh[nf], acc[mf][nf]);
                acc[mf][nf] = mfma_bf16(fah[mf], fbl[nf], acc[mf][nf]);
                acc[mf][nf] = mfma_bf16(fal[mf], fbh[nf], acc[mf][nf]);
            }
    }
#pragma unroll
    for (int mf = 0; mf < 4; ++mf)
#pragma unroll
        for (int nf = 0; nf < 2; ++nf)
#pragma unroll
            for (int r = 0; r < 4; ++r) {
                int grow = m0 + mf * 16 + lq * 4 + r;
                int gcol = n0 + wc * 32 + nf * 16 + lc;
                out[(size_t)grow * 512 + gcol] = acc[mf][nf][r] * seq_mask[grow];
            }
}

// ---------------------------------------------------------------------------
extern "C" void kernel_launch(void* const* d_in, const int* in_sizes, int n_in,
                              void* d_out, int out_size, void* d_ws, size_t ws_size,
                              hipStream_t stream) {
    const float* x         = (const float*)d_in[0];
    const float* timev     = (const float*)d_in[1];
    const float* attn_bias = (const float*)d_in[2];
    const float* seq_mask  = (const float*)d_in[3];
    const float* gamma     = (const float*)d_in[4];
    const float* w_time    = (const float*)d_in[5];
    const float* b_time    = (const float*)d_in[6];
    const float* w_q       = (const float*)d_in[7];
    const float* w_kv      = (const float*)d_in[8];
    const float* w_out     = (const float*)d_in[9];
    float* out = (float*)d_out;

    char* ws = (char*)d_ws;
    size_t off = 0;
    auto alloc = [&](size_t bytes) {
        char* p = ws + off;
        off += (bytes + 255) & ~(size_t)255;
        return p;
    };
    float*          tc   = (float*)alloc(2048 * 4);
    unsigned short* wq   = (unsigned short*)alloc(262144 * 2);
    unsigned short* wkv  = (unsigned short*)alloc(524288 * 2);
    unsigned short* wo_h = (unsigned short*)alloc(262144 * 2);
    unsigned short* wo_l = (unsigned short*)alloc(262144 * 2);
    unsigned short* xbf  = (unsigned short*)alloc(2097152 * 2);
    unsigned short* xnbf = (unsigned short*)alloc(2097152 * 2);
    unsigned short* qb   = (unsigned short*)alloc(2097152 * 2);
    unsigned short* kb   = (unsigned short*)alloc(2097152 * 2);
    unsigned short* vtb  = (unsigned short*)alloc(2097152 * 2);
    unsigned short* ahh  = (unsigned short*)alloc(2097152 * 2);
    unsigned short* all_ = (unsigned short*)alloc(2097152 * 2);

    k_pt<<<4608, 256, 0, stream>>>(w_q, w_kv, w_out, timev, w_time, b_time,
                                   wq, wkv, wo_h, wo_l, tc);
    k_lnfilm<<<1024, 256, 0, stream>>>(x, gamma, seq_mask, tc, xbf, xnbf);
    k_gemm2<<<dim3(32, 12), 256, 0, stream>>>(xnbf, xbf, wq, wkv, qb, kb, vtb);
    k_attn<<<512, 256, 0, stream>>>(qb, kb, vtb, attn_bias, seq_mask, ahh, all_);
    k_gemm_out<<<dim3(64, 4), 256, 0, stream>>>(ahh, all_, wo_h, wo_l, seq_mask, out);
}

// Round 17
// 121.218 us; speedup vs baseline: 1.6429x; 1.6429x over previous
//
#include <hip/hip_runtime.h>
#include <stdint.h>

// ---------------------------------------------------------------------------
// TimeCondAttention on MI355X (gfx950)
// B=2, N=2048, DIM=512, H=8, DH=64, TIME_DIM=512
// R17: REVERT to R15 (best, 123.3us). R16's barrier-free direct-global K/V
//      reads hit the register-allocator load-use serialization trap
//      (VGPR clamped to 76, attn 181us) — gl_lds staging is load-bearing.
//      Only change vs R15: k_gemm_out's duplicate Ah stage cleaned
//      (this cleaned version already ran+passed in R16).
// ---------------------------------------------------------------------------

using s16x8 = __attribute__((ext_vector_type(8))) short;
using f32x4 = __attribute__((ext_vector_type(4))) float;
using u16x4 = __attribute__((ext_vector_type(4))) unsigned short;
using u32x2 = __attribute__((ext_vector_type(2))) unsigned int;

#define EPSV 1e-5f
#define NEGV 1e6f
#define L2E  1.44269504088896341f
// q-projection scale: 0.125 * log2(e)
#define QSCL 0.18033688011112043f

__device__ __forceinline__ unsigned short f2bf(float f) {
    unsigned int u = __float_as_uint(f);
    u += 0x7FFFu + ((u >> 16) & 1u);   // RNE (inputs finite)
    return (unsigned short)(u >> 16);
}
__device__ __forceinline__ float bf2f(unsigned short s) {
    return __uint_as_float((unsigned int)s << 16);
}

__device__ __forceinline__ void gl_lds16(const void* g, void* l) {
    __builtin_amdgcn_global_load_lds((const __attribute__((address_space(1))) void*)g,
                                     (__attribute__((address_space(3))) void*)l, 16, 0, 0);
}

__device__ __forceinline__ f32x4 mfma_bf16(s16x8 a, s16x8 b, f32x4 c) {
    return __builtin_amdgcn_mfma_f32_16x16x32_bf16(a, b, c, 0, 0, 0);
}

// ---------------- K0: fused weight-prep + time GEMV -------------------------
__global__ void k_pt(const float* __restrict__ w_q, const float* __restrict__ w_kv,
                     const float* __restrict__ w_out,
                     const float* __restrict__ timev, const float* __restrict__ w_time,
                     const float* __restrict__ b_time,
                     unsigned short* __restrict__ wq, unsigned short* __restrict__ wkv,
                     unsigned short* __restrict__ wo_h, unsigned short* __restrict__ wo_l,
                     float* __restrict__ tc) {
    if (blockIdx.x < 4096) {
        int idx = blockIdx.x * 256 + threadIdx.x;     // total 1,048,576 exactly
        if (idx < 262144) {
            wq[idx] = f2bf(w_q[idx]);
        } else if (idx < 786432) {
            int i = idx - 262144;
            wkv[i] = f2bf(w_kv[i]);
        } else {
            int i = idx - 786432;
            float v = w_out[i];
            unsigned short h = f2bf(v);
            wo_h[i] = h;
            wo_l[i] = f2bf(v - bf2f(h));
        }
    } else {
        int bid = blockIdx.x - 4096;                  // 0..511
        int wid = threadIdx.x >> 6, lane = threadIdx.x & 63;
        int b = bid >> 8;
        int j = (bid & 255) * 4 + wid;                // 0..1023
        const float* tv = timev + b * 512;
        const float* wr = w_time + (size_t)j * 512;
        float acc = 0.f;
#pragma unroll
        for (int i = 0; i < 8; ++i) {
            int k = i * 64 + lane;
            float t = tv[k];
            float s = t / (1.f + __expf(-t));         // silu
            acc += s * wr[k];
        }
#pragma unroll
        for (int m = 32; m >= 1; m >>= 1) acc += __shfl_xor(acc, m);
        if (lane == 0) tc[b * 1024 + j] = acc + b_time[j];
    }
}

// ---------------- K2: LayerNorm + FiLM + seq_mask, wave-per-row -------------
__global__ void k_lnfilm(const float* __restrict__ x, const float* __restrict__ gamma,
                         const float* __restrict__ seq_mask, const float* __restrict__ tc,
                         unsigned short* __restrict__ xbf, unsigned short* __restrict__ xnbf) {
    int row = blockIdx.x * 4 + (threadIdx.x >> 6);     // grid 1024, 4 rows/block
    int lane = threadIdx.x & 63;
    int b = row >> 11;
    const float* xr = x + (size_t)row * 512 + lane * 8;
    f32x4 x0 = *(const f32x4*)(xr);
    f32x4 x1 = *(const f32x4*)(xr + 4);
    float s = (x0[0] + x0[1]) + (x0[2] + x0[3]) + (x1[0] + x1[1]) + (x1[2] + x1[3]);
    float sq = x0[0] * x0[0];
    sq = __builtin_fmaf(x0[1], x0[1], sq);
    sq = __builtin_fmaf(x0[2], x0[2], sq);
    sq = __builtin_fmaf(x0[3], x0[3], sq);
    sq = __builtin_fmaf(x1[0], x1[0], sq);
    sq = __builtin_fmaf(x1[1], x1[1], sq);
    sq = __builtin_fmaf(x1[2], x1[2], sq);
    sq = __builtin_fmaf(x1[3], x1[3], sq);
#pragma unroll
    for (int m = 32; m >= 1; m >>= 1) { s += __shfl_xor(s, m); sq += __shfl_xor(sq, m); }
    float mu = s * (1.f / 512.f);
    float var = sq * (1.f / 512.f) - mu * mu;
    float rs = rsqrtf(var + EPSV);
    float qm = seq_mask[row];
    int j = lane * 8;
    const float* scb = tc + b * 1024 + j;
    f32x4 g0 = *(const f32x4*)(gamma + j);
    f32x4 g1 = *(const f32x4*)(gamma + j + 4);
    f32x4 c0 = *(const f32x4*)(scb);
    f32x4 c1 = *(const f32x4*)(scb + 4);
    f32x4 h0 = *(const f32x4*)(scb + 512);
    f32x4 h1 = *(const f32x4*)(scb + 516);
    u16x4 n0, n1, v0, v1;
#pragma unroll
    for (int e = 0; e < 4; ++e) {
        float o0 = ((x0[e] - mu) * rs * g0[e]) * (c0[e] + 1.f) + h0[e];
        float o1 = ((x1[e] - mu) * rs * g1[e]) * (c1[e] + 1.f) + h1[e];
        n0[e] = f2bf(o0 * qm);
        n1[e] = f2bf(o1 * qm);
        v0[e] = f2bf(x0[e]);
        v1[e] = f2bf(x1[e]);
    }
    size_t base = (size_t)row * 512 + j;
    *(u16x4*)(xnbf + base)     = n0;
    *(u16x4*)(xnbf + base + 4) = n1;
    *(u16x4*)(xbf + base)      = v0;
    *(u16x4*)(xbf + base + 4)  = v1;
}

// ---------------- K3: fused q-proj + kv-proj GEMMs ---------------------------
__launch_bounds__(256)
__global__ void k_gemm2(const unsigned short* __restrict__ xnbf,
                        const unsigned short* __restrict__ xbf,
                        const unsigned short* __restrict__ wq,
                        const unsigned short* __restrict__ wkv,
                        unsigned short* __restrict__ qb,
                        unsigned short* __restrict__ kb,
                        unsigned short* __restrict__ vtb) {
    __shared__ unsigned short a_t[128 * 64];
    __shared__ unsigned short b_t[128 * 64];
    int tid = threadIdx.x, lane = tid & 63, wid = tid >> 6;
    int lc = lane & 15, lq = lane >> 4;
    int wr = wid >> 1, wc = wid & 1;
    bool isQ = blockIdx.y < 4;
    int m0 = blockIdx.x * 128;
    int n0 = (isQ ? blockIdx.y : blockIdx.y - 4) * 128;
    const unsigned short* A = isQ ? xnbf : xbf;
    const unsigned short* W = isQ ? wq : wkv;
    f32x4 acc[4][4];
#pragma unroll
    for (int i = 0; i < 4; ++i)
#pragma unroll
        for (int jn = 0; jn < 4; ++jn)
#pragma unroll
            for (int e = 0; e < 4; ++e) acc[i][jn][e] = 0.f;
    const unsigned short* Ab = A + (size_t)m0 * 512;
    const unsigned short* Wb = W + (size_t)n0 * 512;
    int wbase = wid * 64;
    for (int kt = 0; kt < 8; ++kt) {
        __syncthreads();
#pragma unroll
        for (int i = 0; i < 4; ++i) {
            int p = i * 256 + wbase + lane;
            int row = p >> 3, ls = (p & 7) ^ (row & 7);
            gl_lds16(Ab + (size_t)row * 512 + kt * 64 + ls * 8, a_t + (i * 256 + wbase) * 8);
            gl_lds16(Wb + (size_t)row * 512 + kt * 64 + ls * 8, b_t + (i * 256 + wbase) * 8);
        }
        __syncthreads();
        s16x8 af[4][2], bw[4][2];
        const char* ab = (const char*)a_t;
        const char* bb = (const char*)b_t;
#pragma unroll
        for (int mf = 0; mf < 4; ++mf) {
            int row = wr * 64 + mf * 16 + lc;
            int key = (row & 7) << 4;
            af[mf][0] = *(const s16x8*)(ab + row * 128 + ((lq * 16) ^ key));
            af[mf][1] = *(const s16x8*)(ab + row * 128 + ((64 + lq * 16) ^ key));
        }
#pragma unroll
        for (int nf = 0; nf < 4; ++nf) {
            int row = wc * 64 + nf * 16 + lc;
            int key = (row & 7) << 4;
            bw[nf][0] = *(const s16x8*)(bb + row * 128 + ((lq * 16) ^ key));
            bw[nf][1] = *(const s16x8*)(bb + row * 128 + ((64 + lq * 16) ^ key));
        }
#pragma unroll
        for (int mf = 0; mf < 4; ++mf)
#pragma unroll
            for (int nf = 0; nf < 4; ++nf) {
                acc[mf][nf] = mfma_bf16(af[mf][0], bw[nf][0], acc[mf][nf]);
                acc[mf][nf] = mfma_bf16(af[mf][1], bw[nf][1], acc[mf][nf]);
            }
    }
#pragma unroll
    for (int mf = 0; mf < 4; ++mf)
#pragma unroll
        for (int nf = 0; nf < 4; ++nf) {
            int grow0 = m0 + wr * 64 + mf * 16 + lq * 4;
            int gcol = n0 + wc * 64 + nf * 16 + lc;
            int b = grow0 >> 11, nb = grow0 & 2047;
            if (isQ) {
                int h = gcol >> 6, d = gcol & 63;
#pragma unroll
                for (int r = 0; r < 4; ++r)
                    qb[((size_t)((b * 8 + h) * 2048 + nb + r)) * 64 + d] =
                        f2bf(acc[mf][nf][r] * QSCL);
            } else if (gcol < 512) {
                int h = gcol >> 6, d = gcol & 63;
#pragma unroll
                for (int r = 0; r < 4; ++r)
                    kb[((size_t)((b * 8 + h) * 2048 + nb + r)) * 64 + d] = f2bf(acc[mf][nf][r]);
            } else {
                int jj = gcol & 511;
                int h = jj >> 6, d = jj & 63;
                u16x4 vv;
#pragma unroll
                for (int r = 0; r < 4; ++r) vv[r] = f2bf(acc[mf][nf][r]);
                *(u16x4*)(vtb + ((size_t)((b * 8 + h) * 64 + d)) * 2048 + nb) = vv;
            }
        }
}

// ---------------- K4: flash attention (R14/R15, unchanged) ------------------
__launch_bounds__(256)
__global__ void k_attn(const unsigned short* __restrict__ qg, const unsigned short* __restrict__ kg,
                       const unsigned short* __restrict__ vt, const float* __restrict__ bias,
                       const float* __restrict__ seq_mask,
                       unsigned short* __restrict__ ah, unsigned short* __restrict__ al) {
    __shared__ unsigned short k_ring[2][64 * 64];     // [key][d] swz8, 8KB/slot
    __shared__ unsigned short v_ring[2][64 * 64];     // [d][key] swz8, 8KB/slot
    __shared__ __align__(16) char b_ring[2][16384];   // bias [64 rows][256B], swz
    __shared__ __align__(16) char scr[4][2048];       // per-wave P scratch
    __shared__ __align__(16) float km_lds[2048];      // seq_mask for batch b (8KB)

    int tid = threadIdx.x, lane = tid & 63, w = tid >> 6;
    int lc = lane & 15, lq = lane >> 4;

    // XCD mapping: 512 blocks; XCD c hosts bh {2c,2c+1} (K/V L2-resident)
    int lin = blockIdx.x;
    int vid = (lin & 7) * 64 + (lin >> 3);
    int bh = vid >> 5;
    int q0 = (vid & 31) * 64 + w * 16;
    int b = bh >> 3, h = bh & 7;

    const unsigned short* qbase = qg + ((size_t)bh * 2048 + q0) * 64;
    s16x8 aq0 = *(const s16x8*)(qbase + lc * 64 + lq * 8);
    s16x8 aq1 = *(const s16x8*)(qbase + lc * 64 + 32 + lq * 8);

    const unsigned short* kb = kg + (size_t)bh * 2048 * 64;
    const unsigned short* vt0 = vt + (size_t)bh * 64 * 2048;
    const float* bqb = bias + ((size_t)bh * 2048 + q0) * 2048;   // wave's 16 rows
    const float* sk = seq_mask + b * 2048;
    const float NEG2 = NEGV * L2E;
    float qm_ = seq_mask[b * 2048 + q0 + lc];

    char* pw = &scr[w][0];
    int swz = (lc & 7) << 4;
    int brow = lane >> 4, bchk = lane & 15;            // bias load mapping

    float mst = -1e30f, lst = 0.f;
    f32x4 acc[4];
#pragma unroll
    for (int df = 0; df < 4; ++df)
#pragma unroll
        for (int e = 0; e < 4; ++e) acc[df][e] = 0.f;

    auto issue_k = [&](int tile, int slot) {
#pragma unroll
        for (int i = 0; i < 2; ++i) {
            int off = w * 2048 + i * 1024 + lane * 16;
            int row = off >> 7;
            int cc = ((off >> 4) & 7) ^ (row & 7);
            gl_lds16(kb + ((size_t)tile * 64 + row) * 64 + cc * 8,
                     (char*)k_ring[slot] + w * 2048 + i * 1024);
        }
    };
    auto issue_vt = [&](int tile, int slot) {
#pragma unroll
        for (int i = 0; i < 2; ++i) {
            int off = w * 2048 + i * 1024 + lane * 16;
            int row = off >> 7;
            int cc = ((off >> 4) & 7) ^ (row & 7);
            gl_lds16(vt0 + (size_t)row * 2048 + tile * 64 + cc * 8,
                     (char*)v_ring[slot] + w * 2048 + i * 1024);
        }
    };
    // bias: instr i = rows 4i..4i+3 of wave's 16; 4x256B contiguous segments.
    auto issue_b = [&](int tile, int slot) {
#pragma unroll
        for (int i = 0; i < 4; ++i) {
            int row = i * 4 + brow;                    // wave-local 0..15
            int kc = bchk ^ (row & 7);                 // 16B chunk index
            gl_lds16(bqb + (size_t)row * 2048 + tile * 64 + kc * 4,
                     (char*)b_ring[slot] + w * 4096 + i * 1024);
        }
    };

    // ---- prologue: KV(0)+bias(0) -> slot0; km -> LDS; drain; barrier ----
    issue_k(0, 0);
    issue_vt(0, 0);
    issue_b(0, 0);
#pragma unroll
    for (int i = 0; i < 2; ++i)   // seq_mask -> LDS (2KB/wave, lane-linear)
        gl_lds16(sk + w * 512 + i * 256 + lane * 4,
                 (char*)km_lds + w * 2048 + i * 1024);
    __builtin_amdgcn_sched_barrier(0);
    asm volatile("s_waitcnt vmcnt(0)");
    __builtin_amdgcn_s_barrier();
    __builtin_amdgcn_sched_barrier(0);

    auto iter = [&](int kt, int par) {
        const int slot_nxt = par ^ 1;

        // ---- phase A: prefetch KV(kt+1) then bias(kt+1) ----
        {
            int tk = (kt + 1 < 32) ? kt + 1 : 31;
            issue_k(tk, slot_nxt);
            issue_vt(tk, slot_nxt);
            __builtin_amdgcn_sched_barrier(0);
            issue_b(tk, slot_nxt);
        }
        __builtin_amdgcn_sched_barrier(0);

        // ---- phase B: S^T = K Q^T (log2-domain Q) ----
        const char* klds = (const char*)k_ring[par];
        f32x4 sv[4];
        __builtin_amdgcn_s_setprio(1);
#pragma unroll
        for (int nf = 0; nf < 4; ++nf) {
            int row = nf * 16 + lc;
            s16x8 b0 = *(const s16x8*)(klds + row * 128 + ((lq * 16) ^ swz));
            s16x8 b1 = *(const s16x8*)(klds + row * 128 + ((64 + lq * 16) ^ swz));
            f32x4 z;
            z[0] = 0.f; z[1] = 0.f; z[2] = 0.f; z[3] = 0.f;
            z = mfma_bf16(b0, aq0, z);
            z = mfma_bf16(b1, aq1, z);
            sv[nf] = z;
        }
        __builtin_amdgcn_s_setprio(0);

        // ---- phase C: bias from LDS (vmcnt(8): newest 8 = KV+bias(kt+1) fly;
        //      bias(kt) — issued 1 iter ago — is gated but already landed) ----
        __builtin_amdgcn_sched_barrier(0);
        asm volatile("s_waitcnt vmcnt(8)");
        __builtin_amdgcn_sched_barrier(0);
        const char* bws = (const char*)b_ring[par] + w * 4096;
        f32x4 bv[4], km[4];
#pragma unroll
        for (int nf = 0; nf < 4; ++nf) {
            bv[nf] = *(const f32x4*)(bws + lc * 256 + ((((nf << 2) + lq) ^ (lc & 7)) << 4));
            km[nf] = *(const f32x4*)((const char*)km_lds + kt * 256 + nf * 64 + lq * 16);
        }

        // ---- phase D: bias*log2e + mask penalty (exact 0 when unmasked) ----
#pragma unroll
        for (int nf = 0; nf < 4; ++nf) {
#pragma unroll
            for (int e = 0; e < 4; ++e) {
                float pen = __builtin_fmaf(km[nf][e], qm_, -1.0f) * NEG2;
                sv[nf][e] = __builtin_fmaf(bv[nf][e], L2E, sv[nf][e]) + pen;
            }
        }

        // ---- phase E: online softmax, defer-max, cvt_pk P store ----
        f32x4 m4 = sv[0];
#pragma unroll
        for (int nf = 1; nf < 4; ++nf)
#pragma unroll
            for (int e = 0; e < 4; ++e) m4[e] = fmaxf(m4[e], sv[nf][e]);
        float mx = fmaxf(fmaxf(m4[0], m4[1]), fmaxf(m4[2], m4[3]));
        mx = fmaxf(mx, __shfl_xor(mx, 16));
        mx = fmaxf(mx, __shfl_xor(mx, 32));
        if (!__all(mx <= mst + 11.54f)) {
            float mn = fmaxf(mst, mx);
            float scl = __builtin_amdgcn_exp2f(mst - mn);
            lst *= scl;
#pragma unroll
            for (int df = 0; df < 4; ++df)
#pragma unroll
                for (int e = 0; e < 4; ++e) acc[df][e] *= scl;
            mst = mn;
        }
        float rsum = 0.f;
#pragma unroll
        for (int nf = 0; nf < 4; ++nf) {
            f32x4 p;
#pragma unroll
            for (int e = 0; e < 4; ++e) {
                p[e] = __builtin_amdgcn_exp2f(sv[nf][e] - mst);
                rsum += p[e];
            }
            unsigned int pk01, pk23;
            asm("v_cvt_pk_bf16_f32 %0, %1, %2" : "=v"(pk01) : "v"(p[0]), "v"(p[1]));
            asm("v_cvt_pk_bf16_f32 %0, %1, %2" : "=v"(pk23) : "v"(p[2]), "v"(p[3]));
            u32x2 pkv;
            pkv[0] = pk01; pkv[1] = pk23;
            *(u32x2*)(pw + lc * 128 + ((nf * 32 + lq * 8) ^ swz)) = pkv;
        }
        rsum += __shfl_xor(rsum, 16);
        rsum += __shfl_xor(rsum, 32);
        lst += rsum;

        __builtin_amdgcn_sched_barrier(0);
        asm volatile("s_waitcnt lgkmcnt(0)");   // P visible (wave-local)
        __builtin_amdgcn_sched_barrier(0);      // rule #18

        // ---- phase F: O^T += V^T P^T ----
        s16x8 ap0 = *(const s16x8*)(pw + lc * 128 + ((lq * 16) ^ swz));
        s16x8 ap1 = *(const s16x8*)(pw + lc * 128 + ((64 + lq * 16) ^ swz));
        const char* vlds = (const char*)v_ring[par];
        __builtin_amdgcn_s_setprio(1);
#pragma unroll
        for (int df = 0; df < 4; ++df) {
            int row = df * 16 + lc;
            int key = (row & 7) << 4;
            s16x8 av0 = *(const s16x8*)(vlds + row * 128 + ((lq * 16) ^ key));
            s16x8 av1 = *(const s16x8*)(vlds + row * 128 + ((64 + lq * 16) ^ key));
            acc[df] = mfma_bf16(av0, ap0, acc[df]);
            acc[df] = mfma_bf16(av1, ap1, acc[df]);
        }
        __builtin_amdgcn_s_setprio(0);

        // ---- tail: KV(kt+1) landed; bias(kt+1) (newest 4) flies on ----
        __builtin_amdgcn_sched_barrier(0);
        asm volatile("s_waitcnt vmcnt(4) lgkmcnt(0)");
        __builtin_amdgcn_s_barrier();
        __builtin_amdgcn_sched_barrier(0);
    };

    for (int t = 0; t < 16; ++t) {
        iter(2 * t,     0);
        iter(2 * t + 1, 1);
    }
    asm volatile("s_waitcnt vmcnt(0)");   // retire dangling clamped prefetches

    // ---- epilogue: O[q=lc][d], hi/lo bf16 split for precise out-proj ----
    float inv = 1.f / lst;
    size_t rowb = ((size_t)(b * 2048 + q0 + lc)) * 512 + h * 64;
#pragma unroll
    for (int df = 0; df < 4; ++df) {
        u16x4 hi, lo;
#pragma unroll
        for (int r = 0; r < 4; ++r) {
            float o = acc[df][r] * inv;
            unsigned short hb = f2bf(o);
            hi[r] = hb;
            lo[r] = f2bf(o - bf2f(hb));
        }
        *(u16x4*)(ah + rowb + df * 16 + lq * 4) = hi;
        *(u16x4*)(al + rowb + df * 16 + lq * 4) = lo;
    }
}

// ---------------- K5: out proj, 64x128 tile (grid 256 = 1 block/CU) ---------
__launch_bounds__(256)
__global__ void k_gemm_out(const unsigned short* __restrict__ Ah, const unsigned short* __restrict__ Al,
                           const unsigned short* __restrict__ Wh, const unsigned short* __restrict__ Wl,
                           const float* __restrict__ seq_mask, float* __restrict__ out) {
    __shared__ unsigned short ah_t[64 * 32], al_t[64 * 32], bh_t[128 * 32], bl_t[128 * 32];
    int tid = threadIdx.x, lane = tid & 63, wid = tid >> 6;
    int lc = lane & 15, lq = lane >> 4;
    int wc = wid;                                      // 0..3: N-slice of 32
    int m0 = blockIdx.x * 64, n0 = blockIdx.y * 128;
    f32x4 acc[4][2];
#pragma unroll
    for (int i = 0; i < 4; ++i)
#pragma unroll
        for (int jn = 0; jn < 2; ++jn)
#pragma unroll
            for (int e = 0; e < 4; ++e) acc[i][jn][e] = 0.f;
    int wbase = wid * 64;
    for (int kt = 0; kt < 16; ++kt) {
        __syncthreads();
        {
            int p = wbase + lane;
            int row = p >> 2, ls = (p & 3) ^ (row & 3);
            size_t asrc = (size_t)(m0 + row) * 512 + kt * 32 + ls * 8;
            gl_lds16(Ah + asrc, ah_t + wbase * 8);
            gl_lds16(Al + asrc, al_t + wbase * 8);
        }
#pragma unroll
        for (int i = 0; i < 2; ++i) {
            int p = i * 256 + wbase + lane;
            int row = p >> 2, ls = (p & 3) ^ (row & 3);
            size_t bsrc = (size_t)(n0 + row) * 512 + kt * 32 + ls * 8;
            gl_lds16(Wh + bsrc, bh_t + (i * 256 + wbase) * 8);
            gl_lds16(Wl + bsrc, bl_t + (i * 256 + wbase) * 8);
        }
        __syncthreads();
        s16x8 fah[4], fal[4], fbh[2], fbl[2];
#pragma unroll
        for (int mf = 0; mf < 4; ++mf) {
            int row = mf * 16 + lc;
            int off = row * 64 + ((lq * 16) ^ ((row & 3) << 4));
            fah[mf] = *(const s16x8*)((const char*)ah_t + off);
            fal[mf] = *(const s16x8*)((const char*)al_t + off);
        }
#pragma unroll
        for (int nf = 0; nf < 2; ++nf) {
            int row = wc * 32 + nf * 16 + lc;
            int off = row * 64 + ((lq * 16) ^ ((row & 3) << 4));
            fbh[nf] = *(const s16x8*)((const char*)bh_t + off);
            fbl[nf] = *(const s16x8*)((const char*)bl_t + off);
        }
#pragma unroll
        for (int mf = 0; mf < 4; ++mf)
#pragma unroll
            for (int nf = 0; nf < 2; ++nf) {
                acc[mf][nf] = mfma_bf16(fah[mf], fbh[nf], acc[mf][nf]);
                acc[mf][nf] = mfma_bf16(fah[mf], fbl[nf], acc[mf][nf]);
                acc[mf][nf] = mfma_bf16(fal[mf], fbh[nf], acc[mf][nf]);
            }
    }
#pragma unroll
    for (int mf = 0; mf < 4; ++mf)
#pragma unroll
        for (int nf = 0; nf < 2; ++nf)
#pragma unroll
            for (int r = 0; r < 4; ++r) {
                int grow = m0 + mf * 16 + lq * 4 + r;
                int gcol = n0 + wc * 32 + nf * 16 + lc;
                out[(size_t)grow * 512 + gcol] = acc[mf][nf][r] * seq_mask[grow];
            }
}

// ---------------------------------------------------------------------------
extern "C" void kernel_launch(void* const* d_in, const int* in_sizes, int n_in,
                              void* d_out, int out_size, void* d_ws, size_t ws_size,
                              hipStream_t stream) {
    const float* x         = (const float*)d_in[0];
    const float* timev     = (const float*)d_in[1];
    const float* attn_bias = (const float*)d_in[2];
    const float* seq_mask  = (const float*)d_in[3];
    const float* gamma     = (const float*)d_in[4];
    const float* w_time    = (const float*)d_in[5];
    const float* b_time    = (const float*)d_in[6];
    const float* w_q       = (const float*)d_in[7];
    const float* w_kv      = (const float*)d_in[8];
    const float* w_out     = (const float*)d_in[9];
    float* out = (float*)d_out;

    char* ws = (char*)d_ws;
    size_t off = 0;
    auto alloc = [&](size_t bytes) {
        char* p = ws + off;
        off += (bytes + 255) & ~(size_t)255;
        return p;
    };
    float*          tc   = (float*)alloc(2048 * 4);
    unsigned short* wq   = (unsigned short*)alloc(262144 * 2);
    unsigned short* wkv  = (unsigned short*)alloc(524288 * 2);
    unsigned short* wo_h = (unsigned short*)alloc(262144 * 2);
    unsigned short* wo_l = (unsigned short*)alloc(262144 * 2);
    unsigned short* xbf  = (unsigned short*)alloc(2097152 * 2);
    unsigned short* xnbf = (unsigned short*)alloc(2097152 * 2);
    unsigned short* qb   = (unsigned short*)alloc(2097152 * 2);
    unsigned short* kb   = (unsigned short*)alloc(2097152 * 2);
    unsigned short* vtb  = (unsigned short*)alloc(2097152 * 2);
    unsigned short* ahh  = (unsigned short*)alloc(2097152 * 2);
    unsigned short* all_ = (unsigned short*)alloc(2097152 * 2);

    k_pt<<<4608, 256, 0, stream>>>(w_q, w_kv, w_out, timev, w_time, b_time,
                                   wq, wkv, wo_h, wo_l, tc);
    k_lnfilm<<<1024, 256, 0, stream>>>(x, gamma, seq_mask, tc, xbf, xnbf);
    k_gemm2<<<dim3(32, 12), 256, 0, stream>>>(xnbf, xbf, wq, wkv, qb, kb, vtb);
    k_attn<<<512, 256, 0, stream>>>(qb, kb, vtb, attn_bias, seq_mask, ahh, all_);
    k_gemm_out<<<dim3(64, 4), 256, 0, stream>>>(ahh, all_, wo_h, wo_l, seq_mask, out);
}